// Round 7
// baseline (170.939 us; speedup 1.0000x reference)
//
#include <hip/hip_runtime.h>
#include <math.h>

#define N_ 4
#define C_ 64
#define H_ 128
#define W_ 128
#define HW_ (H_ * W_)
#define K2_ 9
#define COUT 64
#define CK 576          // K = 9 taps * 64 channels, order k*64+c

typedef __bf16 bf16x8 __attribute__((ext_vector_type(8)));
typedef float floatx4 __attribute__((ext_vector_type(4)));
typedef float floatx8 __attribute__((ext_vector_type(8)));

// ---- prep: (a) NCHW fp32 -> NHWC bf16 transpose, (b) weight re-layout ----
// grid (5, 128, 4): bx<4 transpose a 32-wide strip; bx==4 does weights.
__global__ __launch_bounds__(256) void prep_kernel(const float* __restrict__ x,
                                                   const float* __restrict__ w,
                                                   const float* __restrict__ w_off,
                                                   __bf16* __restrict__ xT,
                                                   __bf16* __restrict__ w2,
                                                   __bf16* __restrict__ w_off2) {
    __shared__ float s_t[64][33];
    int t = threadIdx.x;
    int bx = blockIdx.x;
    int y = blockIdx.y, n = blockIdx.z;
    if (bx < 4) {
        int x0 = bx * 32;
        int c = t >> 2, seg = (t & 3) * 8;
        const float* src = x + (((size_t)n * C_ + c) * H_ + y) * W_ + x0 + seg;
        floatx4 v0 = *(const floatx4*)src;
        floatx4 v1 = *(const floatx4*)(src + 4);
#pragma unroll
        for (int j = 0; j < 4; ++j) { s_t[c][seg + j] = v0[j]; s_t[c][seg + 4 + j] = v1[j]; }
        __syncthreads();
        int xl = t >> 3, cb = (t & 7) * 8;
        bf16x8 o;
#pragma unroll
        for (int j = 0; j < 8; ++j) o[j] = (__bf16)s_t[cb + j][xl];
        *(bf16x8*)(xT + (((size_t)n * H_ + y) * W_ + x0 + xl) * C_ + cb) = o;
    } else {
        int linear = (n * 128 + y) * 256 + t;
        if (linear < COUT * CK) {
            int o = linear / CK, r = linear - o * CK;
            int k = r >> 6, c = r & 63;
            w2[linear] = (__bf16)w[(o * C_ + c) * K2_ + k];
        }
        if (linear < 32 * CK) {
            int o = linear / CK, r = linear - o * CK;
            int k = r >> 6, c = r & 63;
            w_off2[linear] = (o < 27) ? (__bf16)w_off[(o * C_ + c) * K2_ + k] : (__bf16)0.f;
        }
    }
}

// ---- fused: one wave per 16-pixel tile; B-fragments direct from global NHWC ----
__global__ __launch_bounds__(256, 3) void fused_kernel(const __bf16* __restrict__ xT,
                                                       const __bf16* __restrict__ w2,
                                                       const __bf16* __restrict__ w_off2,
                                                       const float* __restrict__ b_off,
                                                       const float* __restrict__ b,
                                                       float* __restrict__ out) {
    __shared__ float   s_om[4][32 * 16];       // per-wave offset-conv out [co][p]
    __shared__ floatx4 s_w4[4][K2_ * 16];      // per-wave position weights
    __shared__ int     s_pix[4][K2_ * 16];     // per-wave clamped base pixel

    int t = threadIdx.x;
    int lane = t & 63;
    int wv = t >> 6;
    int tile = blockIdx.x * 4 + wv;            // 4096 tiles of 16 pixels
    int pixbase = tile * 16;
    int wo0 = pixbase & (W_ - 1);
    int ho  = (pixbase >> 7) & (H_ - 1);
    int n   = pixbase >> 14;
    const __bf16* xn = xT + (size_t)n * HW_ * C_;

    int p = lane & 15;       // pixel (B col) == A row index bits
    int q = lane >> 4;       // k-chunk quad

    // integer taps for offset conv (per-lane pixel p)
    int  pixk[9];
    bool vk[9];
#pragma unroll
    for (int k = 0; k < 9; ++k) {
        int kh = k / 3, kw = k - kh * 3;
        int y  = ho - 1 + kh;
        int xx = wo0 + p - 1 + kw;
        vk[k] = ((unsigned)y < (unsigned)H_) && ((unsigned)xx < (unsigned)W_);
        int yc = min(max(y, 0), H_ - 1), xc = min(max(xx, 0), W_ - 1);
        pixk[k] = yc * W_ + xc;
    }

    const bf16x8 bz = {(__bf16)0.f, (__bf16)0.f, (__bf16)0.f, (__bf16)0.f,
                       (__bf16)0.f, (__bf16)0.f, (__bf16)0.f, (__bf16)0.f};

    // ---- offset conv: D[32][16] over K=576, B-frags direct from global ----
    floatx4 ao0 = {0.f, 0.f, 0.f, 0.f}, ao1 = {0.f, 0.f, 0.f, 0.f};
    {
        const __bf16* ar0 = w_off2 + (size_t)p * CK + q * 8;
        const __bf16* ar1 = w_off2 + (size_t)(16 + p) * CK + q * 8;
#pragma unroll 3
        for (int k = 0; k < 9; ++k) {
            const __bf16* base = xn + (size_t)pixk[k] * C_ + q * 8;
#pragma unroll
            for (int half = 0; half < 2; ++half) {
                bf16x8 bb = *(const bf16x8*)(base + half * 32);
                bb = vk[k] ? bb : bz;
                int ks = k * 64 + half * 32;
                ao0 = __builtin_amdgcn_mfma_f32_16x16x32_bf16(*(const bf16x8*)(ar0 + ks), bb, ao0, 0, 0, 0);
                ao1 = __builtin_amdgcn_mfma_f32_16x16x32_bf16(*(const bf16x8*)(ar1 + ks), bb, ao1, 0, 0, 0);
            }
        }
    }
    {
        float* om = &s_om[wv][0];
#pragma unroll
        for (int r = 0; r < 4; ++r) {
            om[(q * 4 + r) * 16 + p]        = ao0[r];
            om[(16 + q * 4 + r) * 16 + p]   = ao1[r];
        }
    }
    __syncthreads();

    // ---- coords for all 4 tiles (576 items over 256 threads) ----
#pragma unroll
    for (int it = 0; it < 3; ++it) {
        int i = it * 256 + t;
        if (it < 2 || i < 576) {
            int wv2 = i / 144;
            int P = i - wv2 * 144;
            int k = P >> 4, pp = P & 15;
            int pb2 = (blockIdx.x * 4 + wv2) * 16;
            int wo2 = pb2 & (W_ - 1);
            int ho2 = (pb2 >> 7) & (H_ - 1);
            const float* om2 = &s_om[wv2][0];
            float dy = om2[(2 * k) * 16 + pp]     + b_off[2 * k];
            float dx = om2[(2 * k + 1) * 16 + pp] + b_off[2 * k + 1];
            float mm = om2[(18 + k) * 16 + pp]    + b_off[18 + k];
            float msk = 1.f / (1.f + expf(-mm));
            int kh = k / 3, kw = k - kh * 3;
            float py = (float)(ho2 - 1 + kh) + dy;
            float px = (float)(wo2 + pp - 1 + kw) + dx;
            float yf = floorf(py), xf = floorf(px);
            float fy = py - yf, fx = px - xf;
            int y0 = (int)yf, x0 = (int)xf;
            float wy0 = ((unsigned)y0 < (unsigned)H_)       ? 1.f - fy : 0.f;
            float wy1 = ((unsigned)(y0 + 1) < (unsigned)H_) ? fy       : 0.f;
            float wx0 = ((unsigned)x0 < (unsigned)W_)       ? 1.f - fx : 0.f;
            float wx1 = ((unsigned)(x0 + 1) < (unsigned)W_) ? fx       : 0.f;
            int y0c = min(max(y0, 0), H_ - 2);
            int x0c = min(max(x0, 0), W_ - 2);
            float t0 = (y0 == y0c) ? wy0 : ((y0 + 1 == y0c) ? wy1 : 0.f);
            float t1 = (y0 == y0c) ? wy1 : ((y0 == y0c + 1) ? wy0 : 0.f);
            float u0 = (x0 == x0c) ? wx0 : ((x0 + 1 == x0c) ? wx1 : 0.f);
            float u1 = (x0 == x0c) ? wx1 : ((x0 == x0c + 1) ? wx0 : 0.f);
            floatx4 w4 = { t0 * u0 * msk, t0 * u1 * msk, t1 * u0 * msk, t1 * u1 * msk };
            s_w4[wv2][P] = w4;
            s_pix[wv2][P] = y0c * W_ + x0c;
        }
    }
    __syncthreads();

    // ---- main conv: sample in registers -> MFMA, 4 row-tiles ----
    floatx4 acc0 = {0.f, 0.f, 0.f, 0.f}, acc1 = acc0, acc2 = acc0, acc3 = acc0;
    {
        const __bf16* ar = w2 + (size_t)p * CK + q * 8;
#pragma unroll 3
        for (int k = 0; k < 9; ++k) {
            floatx4 w4 = s_w4[wv][k * 16 + p];
            int pix = s_pix[wv][k * 16 + p];
            const __bf16* base = xn + (size_t)pix * C_ + q * 8;
#pragma unroll
            for (int half = 0; half < 2; ++half) {
                const __bf16* bp = base + half * 32;
                floatx8 t00 = __builtin_convertvector(*(const bf16x8*)(bp), floatx8);
                floatx8 t01 = __builtin_convertvector(*(const bf16x8*)(bp + C_), floatx8);
                floatx8 t10 = __builtin_convertvector(*(const bf16x8*)(bp + W_ * C_), floatx8);
                floatx8 t11 = __builtin_convertvector(*(const bf16x8*)(bp + W_ * C_ + C_), floatx8);
                floatx8 v = t00 * w4[0] + t01 * w4[1] + t10 * w4[2] + t11 * w4[3];
                bf16x8 bb = __builtin_convertvector(v, bf16x8);
                int ks = k * 64 + half * 32;
                acc0 = __builtin_amdgcn_mfma_f32_16x16x32_bf16(*(const bf16x8*)(ar + ks), bb, acc0, 0, 0, 0);
                acc1 = __builtin_amdgcn_mfma_f32_16x16x32_bf16(*(const bf16x8*)(ar + 16 * CK + ks), bb, acc1, 0, 0, 0);
                acc2 = __builtin_amdgcn_mfma_f32_16x16x32_bf16(*(const bf16x8*)(ar + 32 * CK + ks), bb, acc2, 0, 0, 0);
                acc3 = __builtin_amdgcn_mfma_f32_16x16x32_bf16(*(const bf16x8*)(ar + 48 * CK + ks), bb, acc3, 0, 0, 0);
            }
        }
    }

    // ---- epilogue: bias + relu, NCHW stores ----
    {
        float* ob = out + (size_t)n * COUT * HW_ + ho * W_ + wo0 + p;
#pragma unroll
        for (int rt = 0; rt < 4; ++rt) {
            floatx4 a = (rt == 0) ? acc0 : (rt == 1) ? acc1 : (rt == 2) ? acc2 : acc3;
            floatx4 bb4 = *(const floatx4*)(b + rt * 16 + q * 4);
#pragma unroll
            for (int r = 0; r < 4; ++r)
                ob[(size_t)(rt * 16 + q * 4 + r) * HW_] = fmaxf(a[r] + bb4[r], 0.f);
        }
    }
}

extern "C" void kernel_launch(void* const* d_in, const int* in_sizes, int n_in,
                              void* d_out, int out_size, void* d_ws, size_t ws_size,
                              hipStream_t stream) {
    const float* x     = (const float*)d_in[0];
    const float* w_off = (const float*)d_in[1];
    const float* b_off = (const float*)d_in[2];
    const float* w     = (const float*)d_in[3];
    const float* b     = (const float*)d_in[4];
    float* out = (float*)d_out;

    // workspace: xT (NHWC bf16, 8.39 MB) | w2 (64x576 bf16) | w_off2 (32x576 bf16)
    __bf16* xT     = (__bf16*)d_ws;
    __bf16* w2     = xT + (size_t)N_ * HW_ * C_;
    __bf16* w_off2 = w2 + (size_t)COUT * CK;

    prep_kernel<<<dim3(5, 128, 4), 256, 0, stream>>>(x, w, w_off, xT, w2, w_off2);
    fused_kernel<<<1024, 256, 0, stream>>>(xT, w2, w_off2, b_off, b, out);
}

// Round 8
// 136.804 us; speedup vs baseline: 1.2495x; 1.2495x over previous
//
#include <hip/hip_runtime.h>
#include <math.h>

#define N_ 4
#define C_ 64
#define H_ 128
#define W_ 128
#define HW_ (H_ * W_)
#define K2_ 9
#define COUT 64
#define CK 576          // K = 9 taps * 64 channels, order k*64+c
#define TP 16           // pixels per block
#define SST 584         // s_x row stride (elems); row bytes 1168 (16B aligned)

typedef __bf16 bf16x8 __attribute__((ext_vector_type(8)));
typedef __bf16 bf16x2 __attribute__((ext_vector_type(2)));
typedef float floatx4 __attribute__((ext_vector_type(4)));
typedef float floatx2 __attribute__((ext_vector_type(2)));

__device__ __forceinline__ float bflo(unsigned u) {
    return __builtin_bit_cast(float, u << 16);
}
__device__ __forceinline__ float bfhi(unsigned u) {
    return __builtin_bit_cast(float, u & 0xffff0000u);
}

// ---- prep: (a) NCHW fp32 -> NHWC bf16 transpose, (b) weight re-layout ----
// grid (5, 128, 4): bx<4 transpose a 32-wide strip; bx==4 does weights.
__global__ __launch_bounds__(256) void prep_kernel(const float* __restrict__ x,
                                                   const float* __restrict__ w,
                                                   const float* __restrict__ w_off,
                                                   __bf16* __restrict__ xT,
                                                   __bf16* __restrict__ w2,
                                                   __bf16* __restrict__ w_off2) {
    __shared__ float s_t[64][33];
    int t = threadIdx.x;
    int bx = blockIdx.x;
    int y = blockIdx.y, n = blockIdx.z;
    if (bx < 4) {
        int x0 = bx * 32;
        int c = t >> 2, seg = (t & 3) * 8;
        const float* src = x + (((size_t)n * C_ + c) * H_ + y) * W_ + x0 + seg;
        floatx4 v0 = *(const floatx4*)src;
        floatx4 v1 = *(const floatx4*)(src + 4);
#pragma unroll
        for (int j = 0; j < 4; ++j) { s_t[c][seg + j] = v0[j]; s_t[c][seg + 4 + j] = v1[j]; }
        __syncthreads();
        int xl = t >> 3, cb = (t & 7) * 8;
        bf16x8 o;
#pragma unroll
        for (int j = 0; j < 8; ++j) o[j] = (__bf16)s_t[cb + j][xl];
        *(bf16x8*)(xT + (((size_t)n * H_ + y) * W_ + x0 + xl) * C_ + cb) = o;
    } else {
        int linear = (n * 128 + y) * 256 + t;
        if (linear < COUT * CK) {
            int o = linear / CK, r = linear - o * CK;
            int k = r >> 6, c = r & 63;
            w2[linear] = (__bf16)w[(o * C_ + c) * K2_ + k];
        }
        if (linear < 32 * CK) {
            int o = linear / CK, r = linear - o * CK;
            int k = r >> 6, c = r & 63;
            w_off2[linear] = (o < 27) ? (__bf16)w_off[(o * C_ + c) * K2_ + k] : (__bf16)0.f;
        }
    }
}

// bf16 A (global) x bf16 B (LDS) -> 16x16 tile, K order = k*64+c
__device__ __forceinline__ floatx4 gemm_tile(const __bf16* __restrict__ arow,
                                             const __bf16* __restrict__ brow) {
    floatx4 acc = {0.f, 0.f, 0.f, 0.f};
#pragma unroll
    for (int it = 0; it < 18; ++it) {
        bf16x8 a  = *(const bf16x8*)(arow + 32 * it);
        bf16x8 bb = *(const bf16x8*)(brow + 32 * it);
        acc = __builtin_amdgcn_mfma_f32_16x16x32_bf16(a, bb, acc, 0, 0, 0);
    }
    return acc;
}

__global__ __launch_bounds__(256) void fused_kernel(const __bf16* __restrict__ xT,
                                                    const __bf16* __restrict__ w2,
                                                    const __bf16* __restrict__ w_off2,
                                                    const float* __restrict__ b_off,
                                                    const float* __restrict__ b,
                                                    float* __restrict__ out) {
    __shared__ __align__(16) __bf16 s_x[TP * SST];   // B^T tile [p][k*64+c]
    __shared__ float s_om[32 * TP];                  // offset-conv out [co][p]
    __shared__ floatx4 s_w4[K2_ * TP];               // 4 position-weights (mask folded)
    __shared__ int s_pix[K2_ * TP];                  // clamped base pixel index

    int t = threadIdx.x;
    int pixbase = blockIdx.x * TP;                   // over N*H*W
    int wo0 = pixbase & (W_ - 1);
    int ho  = (pixbase >> 7) & (H_ - 1);
    int n   = pixbase >> 14;
    const __bf16* xn = xT + (size_t)n * HW_ * C_;

    int lane = t & 63;
    int wv   = t >> 6;
    int half = lane >> 5;
    int li   = lane & 31;

    // ---- Phase A: integer-tap im2col (coalesced NHWC reads, 18 loads in flight) ----
    {
        unsigned ua[18];
#pragma unroll
        for (int j = 0; j < 18; ++j) {
            int P = wv * 36 + 2 * j + half;          // P = k*16 + p
            int k = P >> 4, p = P & 15;
            int kh = k / 3, kw = k - kh * 3;
            int y  = ho - 1 + kh;
            int xx = wo0 + p - 1 + kw;
            int yc  = min(max(y, 0), H_ - 1);
            int xc2 = min(max(xx, 0), W_ - 1);
            unsigned pix = (unsigned)(yc * W_ + xc2);
            ua[j] = *(const unsigned*)(xn + (size_t)pix * C_ + 2 * li);
        }
#pragma unroll
        for (int j = 0; j < 18; ++j) {
            int P = wv * 36 + 2 * j + half;
            int k = P >> 4, p = P & 15;
            int kh = k / 3, kw = k - kh * 3;
            int y  = ho - 1 + kh;
            int xx = wo0 + p - 1 + kw;
            bool valid = ((unsigned)y < (unsigned)H_) && ((unsigned)xx < (unsigned)W_);
            unsigned v = valid ? ua[j] : 0u;
            *(unsigned*)&s_x[p * SST + k * 64 + 2 * li] = v;
        }
    }
    __syncthreads();

    int q   = lane >> 4;
    int col = lane & 15;
    const __bf16* brow = s_x + col * SST + q * 8;

    // ---- Phase B: offset conv via MFMA (waves 0,1; rows>=27 unused) ----
    if (wv < 2) {
        int row = min(16 * wv + col, 26);
        floatx4 acc = gemm_tile(w_off2 + (size_t)row * CK + q * 8, brow);
#pragma unroll
        for (int r = 0; r < 4; ++r)
            s_om[(16 * wv + q * 4 + r) * TP + col] = acc[r];
    }
    __syncthreads();

    // ---- coords: position-weights + clamped base pixel (144 threads) ----
    if (t < K2_ * TP) {
        int k  = t >> 4;
        int pp = t & 15;
        float dy = s_om[(2 * k) * TP + pp]     + b_off[2 * k];
        float dx = s_om[(2 * k + 1) * TP + pp] + b_off[2 * k + 1];
        float mm = s_om[(18 + k) * TP + pp]    + b_off[18 + k];
        float msk = 1.f / (1.f + expf(-mm));
        int kh = k / 3, kw = k - kh * 3;
        float py = (float)(ho - 1 + kh) + dy;
        float px = (float)(wo0 + pp - 1 + kw) + dx;
        float yf = floorf(py), xf = floorf(px);
        float fy = py - yf, fx = px - xf;
        int y0 = (int)yf, x0 = (int)xf;
        float wy0 = ((unsigned)y0 < (unsigned)H_)       ? 1.f - fy : 0.f;
        float wy1 = ((unsigned)(y0 + 1) < (unsigned)H_) ? fy       : 0.f;
        float wx0 = ((unsigned)x0 < (unsigned)W_)       ? 1.f - fx : 0.f;
        float wx1 = ((unsigned)(x0 + 1) < (unsigned)W_) ? fx       : 0.f;
        int y0c = min(max(y0, 0), H_ - 2);
        int x0c = min(max(x0, 0), W_ - 2);
        // shift weights onto clamped positions (OOB-safe addresses, exact zeros)
        float t0 = (y0 == y0c) ? wy0 : ((y0 + 1 == y0c) ? wy1 : 0.f);
        float t1 = (y0 == y0c) ? wy1 : ((y0 == y0c + 1) ? wy0 : 0.f);
        float u0 = (x0 == x0c) ? wx0 : ((x0 + 1 == x0c) ? wx1 : 0.f);
        float u1 = (x0 == x0c) ? wx1 : ((x0 == x0c + 1) ? wx0 : 0.f);
        floatx4 w4 = { t0 * u0 * msk, t0 * u1 * msk, t1 * u0 * msk, t1 * u1 * msk };
        s_w4[t] = w4;
        s_pix[t] = y0c * W_ + x0c;
    }
    __syncthreads();

    // ---- Phase C: bilinear sample; half-wave per (k,p), lane = channel pair ----
    // 4 dword loads per group (row0 x0, row0 x1, row1 x0, row1 x1), depth-3 pipeline.
    {
        int Pb = wv * 36 + half;
        unsigned buf[3][4];
#pragma unroll
        for (int g = 0; g < 2; ++g) {               // prologue
            int pix = s_pix[Pb + 2 * g];
            const unsigned* bp = (const unsigned*)(xn + (size_t)pix * C_) + li;
            buf[g][0] = bp[0];
            buf[g][1] = bp[32];
            buf[g][2] = bp[W_ * 32];
            buf[g][3] = bp[W_ * 32 + 32];
        }
#pragma unroll
        for (int g = 0; g < 18; ++g) {
            if (g < 16) {                           // issue group g+2
                int pix = s_pix[Pb + 2 * (g + 2)];
                const unsigned* bp = (const unsigned*)(xn + (size_t)pix * C_) + li;
                unsigned* d = buf[(g + 2) % 3];
                d[0] = bp[0];
                d[1] = bp[32];
                d[2] = bp[W_ * 32];
                d[3] = bp[W_ * 32 + 32];
            }
            int P = Pb + 2 * g;
            floatx4 w4 = s_w4[P];
            const unsigned* a = buf[g % 3];
            float lo = w4[0] * bflo(a[0]) + w4[1] * bflo(a[1])
                     + w4[2] * bflo(a[2]) + w4[3] * bflo(a[3]);
            float hi = w4[0] * bfhi(a[0]) + w4[1] * bfhi(a[1])
                     + w4[2] * bfhi(a[2]) + w4[3] * bfhi(a[3]);
            floatx2 fv = {lo, hi};
            bf16x2 bv = __builtin_convertvector(fv, bf16x2);
            int k = P >> 4, p = P & 15;
            *(unsigned*)&s_x[p * SST + k * 64 + 2 * li] = __builtin_bit_cast(unsigned, bv);
        }
    }
    __syncthreads();

    // ---- Phase D: main conv MFMA (4 waves) + bias + relu ----
    {
        int row = 16 * wv + col;
        floatx4 acc = gemm_tile(w2 + (size_t)row * CK + q * 8, brow);
#pragma unroll
        for (int r = 0; r < 4; ++r) {
            int o = 16 * wv + q * 4 + r;
            float v = acc[r] + b[o];
            out[(((size_t)n * COUT + o) * H_ + ho) * W_ + wo0 + col] = fmaxf(v, 0.f);
        }
    }
}

extern "C" void kernel_launch(void* const* d_in, const int* in_sizes, int n_in,
                              void* d_out, int out_size, void* d_ws, size_t ws_size,
                              hipStream_t stream) {
    const float* x     = (const float*)d_in[0];
    const float* w_off = (const float*)d_in[1];
    const float* b_off = (const float*)d_in[2];
    const float* w     = (const float*)d_in[3];
    const float* b     = (const float*)d_in[4];
    float* out = (float*)d_out;

    // workspace: xT (NHWC bf16, 8.39 MB) | w2 (64x576 bf16) | w_off2 (32x576 bf16)
    __bf16* xT     = (__bf16*)d_ws;
    __bf16* w2     = xT + (size_t)N_ * HW_ * C_;
    __bf16* w_off2 = w2 + (size_t)COUT * CK;

    prep_kernel<<<dim3(5, 128, 4), 256, 0, stream>>>(x, w, w_off, xT, w2, w_off2);

    int nblocks = N_ * H_ * W_ / TP;   // 4096
    fused_kernel<<<nblocks, 256, 0, stream>>>(xT, w2, w_off2, b_off, b, out);
}